// Round 4
// baseline (622.069 us; speedup 1.0000x reference)
//
#include <hip/hip_runtime.h>

// Self-attention B=32,C=256,N=1024 on gfx950.
// S[i,j] = q_i.k_j + rel_i.q_j (K=512 concat), online softmax, O = P V^T.
// R3: swapped S^T (j lane-local rows, i=lq cols) -> softmax 2-shfl, per-lane
// m/lsum, P stays in registers (row-permuted subtiles make P == PV B-fragment).
// 3-buffer LDS ring (48KB) w/ counted vmcnt(4); 3 blocks/CU. Dedicated
// transpose kernel; proj stages xT via global_load_lds. fp16 MFMA, fp32 acc.

#define NB 32
#define NC 256
#define NNN 1024

typedef _Float16 f16;
typedef __attribute__((ext_vector_type(4))) _Float16 half4;
typedef __attribute__((ext_vector_type(8))) _Float16 half8;
typedef __attribute__((ext_vector_type(4))) float f32x4;
typedef __attribute__((ext_vector_type(4))) float float4v;

__device__ __forceinline__ f32x4 mfma16(half8 a, half8 b, f32x4 c) {
  return __builtin_amdgcn_mfma_f32_16x16x32_f16(a, b, c, 0, 0, 0);
}
// async global->LDS, 16B/lane; LDS dest = uniform base + lane*16 (linear).
__device__ __forceinline__ void gload16(const f16* g, f16* l) {
  __builtin_amdgcn_global_load_lds(
      (const __attribute__((address_space(1))) void*)g,
      (__attribute__((address_space(3))) void*)l, 16, 0, 0);
}

// ---------------- prep: W -> fp16 [3][C][C]; RT[n][c] = relw+relh ----------------
__global__ __launch_bounds__(256) void k_prep(
    const float* __restrict__ Wq, const float* __restrict__ Wk,
    const float* __restrict__ Wv, const float* __restrict__ relh,
    const float* __restrict__ relw, f16* __restrict__ Wh, f16* __restrict__ RT) {
  int bid = blockIdx.x, tid = threadIdx.x;
  if (bid < 192) {
    int base = (bid * 256 + tid) * 4;  // [0, 196608)
    int w = base >> 16, j = base & 65535;
    const float* src = (w == 0) ? Wq : ((w == 1) ? Wk : Wv);
    float4v v = *(const float4v*)(src + j);
    Wh[base + 0] = (f16)v.x; Wh[base + 1] = (f16)v.y;
    Wh[base + 2] = (f16)v.z; Wh[base + 3] = (f16)v.w;
  } else {
    int n = bid - 192;  // 0..1023
    int c = tid;
    RT[n * NC + c] = (f16)(relw[c * 32 + (n >> 5)] + relh[c * 32 + (n & 31)]);
  }
}

// ---------------- xpose: x[b][c][n] f32 -> xT[b][n][c] f16, LDS tile ----------------
__global__ __launch_bounds__(256) void k_xpose(
    const float* __restrict__ x, f16* __restrict__ xT) {
  int bid = blockIdx.x;              // 32b * 4ct * 16nt = 2048
  int nt = bid & 15, ct = (bid >> 4) & 3, b = bid >> 6;
  int c0 = ct << 6, n0 = nt << 6;
  __shared__ f16 T[64][72];
  int t = threadIdx.x;
  {
    int cl = t >> 2, n4 = (t & 3) << 4;
    const float* src = x + ((size_t)(b * NC + c0 + cl) << 10) + n0 + n4;
    float4v v0 = *(const float4v*)(src + 0);
    float4v v1 = *(const float4v*)(src + 4);
    float4v v2 = *(const float4v*)(src + 8);
    float4v v3 = *(const float4v*)(src + 12);
    f16* d = &T[cl][n4];
    d[0]=(f16)v0.x; d[1]=(f16)v0.y; d[2]=(f16)v0.z; d[3]=(f16)v0.w;
    d[4]=(f16)v1.x; d[5]=(f16)v1.y; d[6]=(f16)v1.z; d[7]=(f16)v1.w;
    d[8]=(f16)v2.x; d[9]=(f16)v2.y; d[10]=(f16)v2.z; d[11]=(f16)v2.w;
    d[12]=(f16)v3.x; d[13]=(f16)v3.y; d[14]=(f16)v3.z; d[15]=(f16)v3.w;
  }
  __syncthreads();
  {
    int nl = t >> 2, c16 = (t & 3) << 4;
    half8 h0, h1;
    #pragma unroll
    for (int u = 0; u < 8; ++u) h0[u] = T[c16 + u][nl];
    #pragma unroll
    for (int u = 0; u < 8; ++u) h1[u] = T[c16 + 8 + u][nl];
    f16* dst = xT + ((size_t)(b * NNN + n0 + nl) << 8) + c0 + c16;
    *(half8*)(dst) = h0;
    *(half8*)(dst + 8) = h1;
  }
}

// -------- proj: KQ[b][n][0:256]=K row, [256:512]=Q row; V[b][o][n] (fp16) --------
__global__ __launch_bounds__(256, 4) void k_proj(
    const f16* __restrict__ xT, const f16* __restrict__ Wh,
    const float* __restrict__ bq, const float* __restrict__ bk,
    const float* __restrict__ bv,
    f16* __restrict__ KQ, f16* __restrict__ V) {
  int b = blockIdx.x >> 4;
  int n0 = (blockIdx.x & 15) << 6;
  int tid = threadIdx.x;
  int wave = tid >> 6, lane = tid & 63;
  int lq = lane & 15, g = lane >> 4;
  int ow = wave << 6;
  const f16* xTb = xT + ((size_t)(b * NNN + n0) << 8);

  __shared__ f16 XS[64][256];  // 32KB, XOR-swizzled 16B slots

  // stage via gload_lds, pre-swizzled global source
  {
    int li = lane & 31;
    #pragma unroll
    for (int q2 = 0; q2 < 8; ++q2) {
      int r2 = wave * 16 + q2 * 2;
      int r = r2 + (lane >> 5);
      int slot = (li & 0x10) | ((li ^ (r & 15)) & 0xF);
      gload16(xTb + ((size_t)r << 8) + slot * 8, &XS[r2][0]);
    }
  }
  asm volatile("s_waitcnt vmcnt(0)" ::: "memory");
  __syncthreads();

  #pragma unroll 1
  for (int which = 0; which < 2; ++which) {
    const f16* Wp = Wh + which * 65536;
    const float* bias = which ? bk : bq;
    int koff = which ? 0 : 256;
    f32x4 acc[4][4];
    #pragma unroll
    for (int f = 0; f < 4; ++f) {
      float bf = bias[ow + 16 * f + lq];
      #pragma unroll
      for (int mm = 0; mm < 4; ++mm) acc[mm][f] = (f32x4){bf, bf, bf, bf};
    }
    #pragma unroll
    for (int kk = 0; kk < 8; ++kk) {
      int cb = kk * 32 + 8 * g;
      int s = 4 * kk + g;
      int p = (s & 0x10) | ((s ^ lq) & 0xF);
      half8 xa[4], wb[4];
      #pragma unroll
      for (int mm = 0; mm < 4; ++mm)
        xa[mm] = *(const half8*)(&XS[16 * mm + lq][p * 8]);
      #pragma unroll
      for (int f = 0; f < 4; ++f)
        wb[f] = *(const half8*)(Wp + (size_t)(ow + 16 * f + lq) * NC + cb);
      #pragma unroll
      for (int mm = 0; mm < 4; ++mm)
        #pragma unroll
        for (int f = 0; f < 4; ++f)
          acc[mm][f] = mfma16(xa[mm], wb[f], acc[mm][f]);
    }
    #pragma unroll
    for (int mm = 0; mm < 4; ++mm)
      #pragma unroll
      for (int f = 0; f < 4; ++f)
        #pragma unroll
        for (int r = 0; r < 4; ++r)
          KQ[((size_t)(b * NNN + n0 + 16 * mm + 4 * g + r) << 9) + koff + ow + 16 * f + lq] =
              (f16)acc[mm][f][r];
  }

  {
    const f16* Wp = Wh + 2 * 65536;
    f32x4 acc[4][4];
    #pragma unroll
    for (int mm = 0; mm < 4; ++mm)
      #pragma unroll
      for (int r = 0; r < 4; ++r) {
        float bf = bv[ow + 16 * mm + 4 * g + r];
        #pragma unroll
        for (int f = 0; f < 4; ++f) acc[mm][f][r] = bf;
      }
    #pragma unroll
    for (int kk = 0; kk < 8; ++kk) {
      int cb = kk * 32 + 8 * g;
      int s = 4 * kk + g;
      int p = (s & 0x10) | ((s ^ lq) & 0xF);
      half8 va[4], xb2[4];
      #pragma unroll
      for (int mm = 0; mm < 4; ++mm)
        va[mm] = *(const half8*)(Wp + (size_t)(ow + 16 * mm + lq) * NC + cb);
      #pragma unroll
      for (int f = 0; f < 4; ++f)
        xb2[f] = *(const half8*)(&XS[16 * f + lq][p * 8]);
      #pragma unroll
      for (int mm = 0; mm < 4; ++mm)
        #pragma unroll
        for (int f = 0; f < 4; ++f)
          acc[mm][f] = mfma16(va[mm], xb2[f], acc[mm][f]);
    }
    #pragma unroll
    for (int mm = 0; mm < 4; ++mm)
      #pragma unroll
      for (int f = 0; f < 4; ++f)
        #pragma unroll
        for (int r = 0; r < 4; ++r)
          V[((size_t)(b * NC + ow + 16 * mm + 4 * g + r) << 10) + n0 + 16 * f + lq] =
              (f16)acc[mm][f][r];
  }
}

// -------- flash4: swapped S^T, 512 blocks x 4 waves, 64 subtiles of 16 j --------
// Subtile t (jt2=t>>1, p=t&1) holds rows rho=0..15 <-> j = jt2*32 + 8*(rho>>2) + 4p + (rho&3).
// Lane (lq,g) after MFMA: S[r] = S^T[j=jt2*32+8g+4p+r][i=iw+lq]; two subtiles' P
// concat = exact K=32 PV B-fragment (k=8g..8g+7 <-> j=jt2*32+8g..+7). No P LDS.
__global__ __launch_bounds__(256, 3) void k_flash4(
    const f16* __restrict__ KQ, const f16* __restrict__ V,
    const f16* __restrict__ RT, float* __restrict__ out) {
  int bid = blockIdx.x;
  int swz = (bid & 7) * 64 + (bid >> 3);  // batch-per-XCD
  int b = swz >> 4;
  int i0 = (swz & 15) << 6;
  int tid = threadIdx.x;
  int wave = tid >> 6, lane = tid & 63;
  int lq = lane & 15, g = lane >> 4;
  int iw = i0 + 16 * wave;

  __shared__ f16 KQS[3][16][512];  // 48KB ring, stage 2 subtiles ahead

  const f16* KQb = KQ + ((size_t)b << 19);
  const f16* Vb = V + ((size_t)b << 18);

  // B-operand fragments (col i = iw+lq): [Q_i | R_i], hoisted for whole kernel
  half8 QA[16];
  #pragma unroll
  for (int kk = 0; kk < 8; ++kk)
    QA[kk] = *(const half8*)(KQb + ((size_t)(iw + lq) << 9) + 256 + kk * 32 + 8 * g);
  #pragma unroll
  for (int kk = 0; kk < 8; ++kk)
    QA[8 + kk] = *(const half8*)(RT + (size_t)(iw + lq) * NC + kk * 32 + 8 * g);

  f32x4 acc[16];
  #pragma unroll
  for (int cf = 0; cf < 16; ++cf) acc[cf] = (f32x4){0.f, 0.f, 0.f, 0.f};
  float m = -1e30f, lsum = 0.f;  // per-lane (i = iw+lq); lsum partial over g-subset
  half4 pend = (half4){0, 0, 0, 0};

#define STAGE(T, BUF)                                                       \
  {                                                                         \
    int jt2_ = (T) >> 1, p_ = (T) & 1;                                      \
    _Pragma("unroll")                                                       \
    for (int q = 0; q < 4; ++q) {                                           \
      int rho_ = 4 * wave + q;                                              \
      int j_ = jt2_ * 32 + 8 * wave + 4 * p_ + q;                           \
      int slot_ = (lane & 0x30) | ((lane ^ rho_) & 0xF);                    \
      gload16(KQb + ((size_t)j_ << 9) + slot_ * 8, &KQS[BUF][rho_][0]);     \
    }                                                                       \
  }

  STAGE(0, 0);
  STAGE(1, 1);

  int bufc = 0, bufn = 2;
  #pragma unroll 1
  for (int t = 0; t < 64; ++t) {
    if (t < 63) {
      asm volatile("s_waitcnt vmcnt(4)" ::: "memory");  // subtile t landed
    } else {
      asm volatile("s_waitcnt vmcnt(0)" ::: "memory");
    }
    __syncthreads();
    if (t < 62) STAGE(t + 2, bufn);

    // ---- S^T = KQ_tile . [Q|R]_i  (K=512)
    f32x4 S = (f32x4){0.f, 0.f, 0.f, 0.f};
    const f16* KQSc = &KQS[bufc][0][0];
    __builtin_amdgcn_s_setprio(1);
    #pragma unroll
    for (int kk = 0; kk < 16; ++kk) {
      int s = 4 * kk + g;
      int p = (s & 0x30) | ((s ^ lq) & 0xF);
      S = mfma16(*(const half8*)(KQSc + lq * 512 + p * 8), QA[kk], S);
    }
    __builtin_amdgcn_s_setprio(0);

    // ---- online softmax, per-lane state, defer-max THR=8
    float tmax = fmaxf(fmaxf(S[0], S[1]), fmaxf(S[2], S[3]));
    tmax = fmaxf(tmax, __shfl_xor(tmax, 16));
    tmax = fmaxf(tmax, __shfl_xor(tmax, 32));
    bool grow = tmax > m + 8.f;
    if (__builtin_amdgcn_ballot_w64(grow)) {
      float mn = fmaxf(m, tmax);
      float sc = __expf(m - mn);
      m = mn;
      lsum *= sc;
      #pragma unroll
      for (int cf = 0; cf < 16; ++cf) {
        acc[cf][0] *= sc; acc[cf][1] *= sc; acc[cf][2] *= sc; acc[cf][3] *= sc;
      }
      f16 sch = (f16)sc;
      pend[0] *= sch; pend[1] *= sch; pend[2] *= sch; pend[3] *= sch;
    }
    float p0 = __expf(S[0] - m), p1 = __expf(S[1] - m),
          p2 = __expf(S[2] - m), p3 = __expf(S[3] - m);
    lsum += (p0 + p1) + (p2 + p3);

    if ((t & 1) == 0) {
      pend = (half4){(f16)p0, (f16)p1, (f16)p2, (f16)p3};
    } else {
      half8 pa;
      pa[0] = pend[0]; pa[1] = pend[1]; pa[2] = pend[2]; pa[3] = pend[3];
      pa[4] = (f16)p0; pa[5] = (f16)p1; pa[6] = (f16)p2; pa[7] = (f16)p3;
      size_t j0 = (size_t)((t >> 1) * 32 + 8 * g);
      // ---- O^T += V . P^T  (K=32), vv contiguous 16B
      __builtin_amdgcn_s_setprio(1);
      #pragma unroll
      for (int cf = 0; cf < 16; ++cf) {
        half8 vv = *(const half8*)(Vb + ((size_t)(16 * cf + lq) << 10) + j0);
        acc[cf] = mfma16(vv, pa, acc[cf]);
      }
      __builtin_amdgcn_s_setprio(0);
    }
    bufc = (bufc == 2) ? 0 : bufc + 1;
    bufn = (bufn == 2) ? 0 : bufn + 1;
  }
#undef STAGE

  // ---- epilogue: complete lsum across g-groups, normalize, store
  lsum += __shfl_xor(lsum, 16);
  lsum += __shfl_xor(lsum, 32);
  float li = 1.f / lsum;
  #pragma unroll
  for (int cf = 0; cf < 16; ++cf)
    #pragma unroll
    for (int r = 0; r < 4; ++r)
      out[((size_t)(b * NC + 16 * cf + 4 * g + r) << 10) + iw + lq] = acc[cf][r] * li;
}

// ---------------- launch ----------------
extern "C" void kernel_launch(void* const* d_in, const int* in_sizes, int n_in,
                              void* d_out, int out_size, void* d_ws, size_t ws_size,
                              hipStream_t stream) {
  const float* x = (const float*)d_in[0];
  const float* Wq = (const float*)d_in[1];
  const float* bq = (const float*)d_in[2];
  const float* Wk = (const float*)d_in[3];
  const float* bk = (const float*)d_in[4];
  const float* Wv = (const float*)d_in[5];
  const float* bv = (const float*)d_in[6];
  const float* relh = (const float*)d_in[7];
  const float* relw = (const float*)d_in[8];

  char* ws = (char*)d_ws;
  const size_t MB = 1 << 20;
  f16* xT = (f16*)(ws);                         // 16MB
  f16* KQ = (f16*)(ws + 16 * MB);               // 32MB
  f16* V  = (f16*)(ws + 48 * MB);               // 16MB
  f16* RT = (f16*)(ws + 64 * MB);               // 512KB
  f16* Wh = (f16*)(ws + 64 * MB + 512 * 1024);  // 384KB

  k_prep<<<dim3(1216), dim3(256), 0, stream>>>(Wq, Wk, Wv, relh, relw, Wh, RT);
  k_xpose<<<dim3(2048), dim3(256), 0, stream>>>(x, xT);
  k_proj<<<dim3(512), dim3(256), 0, stream>>>(xT, Wh, bq, bk, bv, KQ, V);
  k_flash4<<<dim3(512), dim3(256), 0, stream>>>(KQ, V, RT, (float*)d_out);
}

// Round 5
// 320.799 us; speedup vs baseline: 1.9391x; 1.9391x over previous
//
#include <hip/hip_runtime.h>

// Self-attention B=32,C=256,N=1024 on gfx950.
// S[i,j] = q_i.k_j + rel_i.q_j (K=512 concat), online softmax, O = P V^T.
// R4: flash3's memory discipline (32-row double-buffered tile, stage-at-top,
// vmcnt(0)+barrier at bottom => inter-block L2 lockstep, FETCH ~30MB) fused
// with flash4's swapped-S^T compute (per-lane softmax, register P == PV
// B-fragment, zero bank conflicts). fp16 MFMA, fp32 accum.

#define NB 32
#define NC 256
#define NNN 1024

typedef _Float16 f16;
typedef __attribute__((ext_vector_type(8))) _Float16 half8;
typedef __attribute__((ext_vector_type(4))) float f32x4;
typedef __attribute__((ext_vector_type(4))) float float4v;

__device__ __forceinline__ f32x4 mfma16(half8 a, half8 b, f32x4 c) {
  return __builtin_amdgcn_mfma_f32_16x16x32_f16(a, b, c, 0, 0, 0);
}
// async global->LDS, 16B/lane; LDS dest = uniform base + lane*16 (linear).
__device__ __forceinline__ void gload16(const f16* g, f16* l) {
  __builtin_amdgcn_global_load_lds(
      (const __attribute__((address_space(1))) void*)g,
      (__attribute__((address_space(3))) void*)l, 16, 0, 0);
}

// ---------------- prep: W -> fp16 [3][C][C]; RT[n][c] = relw+relh ----------------
__global__ __launch_bounds__(256) void k_prep(
    const float* __restrict__ Wq, const float* __restrict__ Wk,
    const float* __restrict__ Wv, const float* __restrict__ relh,
    const float* __restrict__ relw, f16* __restrict__ Wh, f16* __restrict__ RT) {
  int bid = blockIdx.x, tid = threadIdx.x;
  if (bid < 192) {
    int base = (bid * 256 + tid) * 4;  // [0, 196608)
    int w = base >> 16, j = base & 65535;
    const float* src = (w == 0) ? Wq : ((w == 1) ? Wk : Wv);
    float4v v = *(const float4v*)(src + j);
    Wh[base + 0] = (f16)v.x; Wh[base + 1] = (f16)v.y;
    Wh[base + 2] = (f16)v.z; Wh[base + 3] = (f16)v.w;
  } else {
    int n = bid - 192;  // 0..1023
    int c = tid;
    RT[n * NC + c] = (f16)(relw[c * 32 + (n >> 5)] + relh[c * 32 + (n & 31)]);
  }
}

// ---------------- xpose: x[b][c][n] f32 -> xT[b][n][c] f16, LDS tile ----------------
__global__ __launch_bounds__(256) void k_xpose(
    const float* __restrict__ x, f16* __restrict__ xT) {
  int bid = blockIdx.x;              // 32b * 4ct * 16nt = 2048
  int nt = bid & 15, ct = (bid >> 4) & 3, b = bid >> 6;
  int c0 = ct << 6, n0 = nt << 6;
  __shared__ f16 T[64][72];
  int t = threadIdx.x;
  {
    int cl = t >> 2, n4 = (t & 3) << 4;
    const float* src = x + ((size_t)(b * NC + c0 + cl) << 10) + n0 + n4;
    float4v v0 = *(const float4v*)(src + 0);
    float4v v1 = *(const float4v*)(src + 4);
    float4v v2 = *(const float4v*)(src + 8);
    float4v v3 = *(const float4v*)(src + 12);
    f16* d = &T[cl][n4];
    d[0]=(f16)v0.x; d[1]=(f16)v0.y; d[2]=(f16)v0.z; d[3]=(f16)v0.w;
    d[4]=(f16)v1.x; d[5]=(f16)v1.y; d[6]=(f16)v1.z; d[7]=(f16)v1.w;
    d[8]=(f16)v2.x; d[9]=(f16)v2.y; d[10]=(f16)v2.z; d[11]=(f16)v2.w;
    d[12]=(f16)v3.x; d[13]=(f16)v3.y; d[14]=(f16)v3.z; d[15]=(f16)v3.w;
  }
  __syncthreads();
  {
    int nl = t >> 2, c16 = (t & 3) << 4;
    half8 h0, h1;
    #pragma unroll
    for (int u = 0; u < 8; ++u) h0[u] = T[c16 + u][nl];
    #pragma unroll
    for (int u = 0; u < 8; ++u) h1[u] = T[c16 + 8 + u][nl];
    f16* dst = xT + ((size_t)(b * NNN + n0 + nl) << 8) + c0 + c16;
    *(half8*)(dst) = h0;
    *(half8*)(dst + 8) = h1;
  }
}

// -------- proj: KQ[b][n][0:256]=K row, [256:512]=Q row; V[b][o][n] (fp16) --------
__global__ __launch_bounds__(256, 4) void k_proj(
    const f16* __restrict__ xT, const f16* __restrict__ Wh,
    const float* __restrict__ bq, const float* __restrict__ bk,
    const float* __restrict__ bv,
    f16* __restrict__ KQ, f16* __restrict__ V) {
  int b = blockIdx.x >> 4;
  int n0 = (blockIdx.x & 15) << 6;
  int tid = threadIdx.x;
  int wave = tid >> 6, lane = tid & 63;
  int lq = lane & 15, g = lane >> 4;
  int ow = wave << 6;
  const f16* xTb = xT + ((size_t)(b * NNN + n0) << 8);

  __shared__ f16 XS[64][256];  // 32KB, XOR-swizzled 16B slots

  {
    int li = lane & 31;
    #pragma unroll
    for (int q2 = 0; q2 < 8; ++q2) {
      int r2 = wave * 16 + q2 * 2;
      int r = r2 + (lane >> 5);
      int slot = (li & 0x10) | ((li ^ (r & 15)) & 0xF);
      gload16(xTb + ((size_t)r << 8) + slot * 8, &XS[r2][0]);
    }
  }
  asm volatile("s_waitcnt vmcnt(0)" ::: "memory");
  __syncthreads();

  #pragma unroll 1
  for (int which = 0; which < 2; ++which) {
    const f16* Wp = Wh + which * 65536;
    const float* bias = which ? bk : bq;
    int koff = which ? 0 : 256;
    f32x4 acc[4][4];
    #pragma unroll
    for (int f = 0; f < 4; ++f) {
      float bf = bias[ow + 16 * f + lq];
      #pragma unroll
      for (int mm = 0; mm < 4; ++mm) acc[mm][f] = (f32x4){bf, bf, bf, bf};
    }
    #pragma unroll
    for (int kk = 0; kk < 8; ++kk) {
      int cb = kk * 32 + 8 * g;
      int s = 4 * kk + g;
      int p = (s & 0x10) | ((s ^ lq) & 0xF);
      half8 xa[4], wb[4];
      #pragma unroll
      for (int mm = 0; mm < 4; ++mm)
        xa[mm] = *(const half8*)(&XS[16 * mm + lq][p * 8]);
      #pragma unroll
      for (int f = 0; f < 4; ++f)
        wb[f] = *(const half8*)(Wp + (size_t)(ow + 16 * f + lq) * NC + cb);
      #pragma unroll
      for (int mm = 0; mm < 4; ++mm)
        #pragma unroll
        for (int f = 0; f < 4; ++f)
          acc[mm][f] = mfma16(xa[mm], wb[f], acc[mm][f]);
    }
    #pragma unroll
    for (int mm = 0; mm < 4; ++mm)
      #pragma unroll
      for (int f = 0; f < 4; ++f)
        #pragma unroll
        for (int r = 0; r < 4; ++r)
          KQ[((size_t)(b * NNN + n0 + 16 * mm + 4 * g + r) << 9) + koff + ow + 16 * f + lq] =
              (f16)acc[mm][f][r];
  }

  {
    const f16* Wp = Wh + 2 * 65536;
    f32x4 acc[4][4];
    #pragma unroll
    for (int mm = 0; mm < 4; ++mm)
      #pragma unroll
      for (int r = 0; r < 4; ++r) {
        float bf = bv[ow + 16 * mm + 4 * g + r];
        #pragma unroll
        for (int f = 0; f < 4; ++f) acc[mm][f][r] = bf;
      }
    #pragma unroll
    for (int kk = 0; kk < 8; ++kk) {
      int cb = kk * 32 + 8 * g;
      int s = 4 * kk + g;
      int p = (s & 0x10) | ((s ^ lq) & 0xF);
      half8 va[4], xb2[4];
      #pragma unroll
      for (int mm = 0; mm < 4; ++mm)
        va[mm] = *(const half8*)(Wp + (size_t)(ow + 16 * mm + lq) * NC + cb);
      #pragma unroll
      for (int f = 0; f < 4; ++f)
        xb2[f] = *(const half8*)(&XS[16 * f + lq][p * 8]);
      #pragma unroll
      for (int mm = 0; mm < 4; ++mm)
        #pragma unroll
        for (int f = 0; f < 4; ++f)
          acc[mm][f] = mfma16(va[mm], xb2[f], acc[mm][f]);
    }
    #pragma unroll
    for (int mm = 0; mm < 4; ++mm)
      #pragma unroll
      for (int f = 0; f < 4; ++f)
        #pragma unroll
        for (int r = 0; r < 4; ++r)
          V[((size_t)(b * NC + ow + 16 * mm + 4 * g + r) << 10) + n0 + 16 * f + lq] =
              (f16)acc[mm][f][r];
  }
}

// -------- flash5: swapped S^T + flash3 memory discipline --------
// Tile jt covers j in [32jt, 32jt+32). Two 16-row LDS subtiles p=0,1:
// subtile row rho <-> j = 32jt + 8*(rho>>2) + 4p + (rho&3).
// After S^T=mfma(KQsub, [Q|R]_i): lane(lq,g) reg r of subtile p = S^T[j=32jt+8g+4p+r][i=iw+lq]
// -> P concat {p0 r0..3, p1 r0..3} IS the K=32 PV B-fragment. No P LDS, per-lane m/lsum.
__global__ __launch_bounds__(256, 2) void k_flash5(
    const f16* __restrict__ KQ, const f16* __restrict__ V,
    const f16* __restrict__ RT, float* __restrict__ out) {
  int bid = blockIdx.x;
  int swz = (bid & 7) * 64 + (bid >> 3);  // 4 batches per XCD
  int b = swz >> 4;
  int i0 = (swz & 15) << 6;
  int tid = threadIdx.x;
  int wave = tid >> 6, lane = tid & 63;
  int lq = lane & 15, g = lane >> 4;
  int iw = i0 + 16 * wave;

  __shared__ f16 KQS[2][2][16][512];  // [buf][p][rho][col], 64KB double buffer

  const f16* KQb = KQ + ((size_t)b << 19);
  const f16* Vb = V + ((size_t)b << 18);

  // B-operand fragments (col i = iw+lq): [Q_i | R_i], hoisted for whole kernel
  half8 QA[16];
  #pragma unroll
  for (int kk = 0; kk < 8; ++kk)
    QA[kk] = *(const half8*)(KQb + ((size_t)(iw + lq) << 9) + 256 + kk * 32 + 8 * g);
  #pragma unroll
  for (int kk = 0; kk < 8; ++kk)
    QA[8 + kk] = *(const half8*)(RT + (size_t)(iw + lq) * NC + kk * 32 + 8 * g);

  f32x4 acc[16];
  #pragma unroll
  for (int cf = 0; cf < 16; ++cf) acc[cf] = (f32x4){0.f, 0.f, 0.f, 0.f};
  float m = -1e30f, lsum = 0.f;  // per-lane (i = iw+lq); lsum partial over this g's j-subset

#define STAGE(JT, BUF)                                                        \
  {                                                                           \
    _Pragma("unroll")                                                         \
    for (int pp = 0; pp < 2; ++pp) {                                          \
      _Pragma("unroll")                                                       \
      for (int q = 0; q < 4; ++q) {                                           \
        int rho_ = 4 * wave + q;                                              \
        int j_ = (JT) * 32 + 8 * wave + 4 * pp + q;                           \
        int slot_ = (lane & 0x30) | ((lane ^ rho_) & 0xF);                    \
        gload16(KQb + ((size_t)j_ << 9) + slot_ * 8, &KQS[BUF][pp][rho_][0]); \
      }                                                                       \
    }                                                                         \
  }

  // prologue
  STAGE(0, 0);
  asm volatile("s_waitcnt vmcnt(0)" ::: "memory");
  __syncthreads();

  #pragma unroll 1
  for (int jt = 0; jt < 32; ++jt) {
    int cur = jt & 1;
    if (jt < 31) {
      if (cur) STAGE(jt + 1, 0) else STAGE(jt + 1, 1);
    }
    // ---- S^T = KQ_sub . [Q|R]_i  (K=512), both subtiles
    f32x4 S0 = (f32x4){0.f, 0.f, 0.f, 0.f};
    f32x4 S1 = (f32x4){0.f, 0.f, 0.f, 0.f};
    const f16* B0 = &KQS[cur][0][lq][0];
    const f16* B1 = &KQS[cur][1][lq][0];
    __builtin_amdgcn_s_setprio(1);
    #pragma unroll
    for (int kk = 0; kk < 16; ++kk) {
      int s = 4 * kk + g;
      int ps = (s & 0x30) | ((s ^ lq) & 0xF);
      S0 = mfma16(*(const half8*)(B0 + ps * 8), QA[kk], S0);
      S1 = mfma16(*(const half8*)(B1 + ps * 8), QA[kk], S1);
    }
    __builtin_amdgcn_s_setprio(0);

    // ---- online softmax, per-lane state, defer-max THR=8
    float tmax = fmaxf(fmaxf(fmaxf(S0[0], S0[1]), fmaxf(S0[2], S0[3])),
                       fmaxf(fmaxf(S1[0], S1[1]), fmaxf(S1[2], S1[3])));
    tmax = fmaxf(tmax, __shfl_xor(tmax, 16));
    tmax = fmaxf(tmax, __shfl_xor(tmax, 32));
    bool grow = tmax > m + 8.f;
    if (__builtin_amdgcn_ballot_w64(grow)) {
      float mn = fmaxf(m, tmax);
      float sc = __expf(m - mn);
      m = mn;
      lsum *= sc;
      #pragma unroll
      for (int cf = 0; cf < 16; ++cf) {
        acc[cf][0] *= sc; acc[cf][1] *= sc; acc[cf][2] *= sc; acc[cf][3] *= sc;
      }
    }
    float p0 = __expf(S0[0] - m), p1 = __expf(S0[1] - m),
          p2 = __expf(S0[2] - m), p3 = __expf(S0[3] - m);
    float p4 = __expf(S1[0] - m), p5 = __expf(S1[1] - m),
          p6 = __expf(S1[2] - m), p7 = __expf(S1[3] - m);
    lsum += ((p0 + p1) + (p2 + p3)) + ((p4 + p5) + (p6 + p7));
    half8 pa;
    pa[0] = (f16)p0; pa[1] = (f16)p1; pa[2] = (f16)p2; pa[3] = (f16)p3;
    pa[4] = (f16)p4; pa[5] = (f16)p5; pa[6] = (f16)p6; pa[7] = (f16)p7;

    // ---- O^T += V . P^T  (K=32), vv contiguous 16B
    size_t j0 = (size_t)(jt * 32 + 8 * g);
    __builtin_amdgcn_s_setprio(1);
    #pragma unroll
    for (int cf = 0; cf < 16; ++cf) {
      half8 vv = *(const half8*)(Vb + ((size_t)(16 * cf + lq) << 10) + j0);
      acc[cf] = mfma16(vv, pa, acc[cf]);
    }
    __builtin_amdgcn_s_setprio(0);

    asm volatile("s_waitcnt vmcnt(0)" ::: "memory");  // prefetch landed
    __syncthreads();
  }
#undef STAGE

  // ---- epilogue: complete lsum across g-groups, normalize, store
  lsum += __shfl_xor(lsum, 16);
  lsum += __shfl_xor(lsum, 32);
  float li = 1.f / lsum;
  #pragma unroll
  for (int cf = 0; cf < 16; ++cf)
    #pragma unroll
    for (int r = 0; r < 4; ++r)
      out[((size_t)(b * NC + 16 * cf + 4 * g + r) << 10) + iw + lq] = acc[cf][r] * li;
}

// ---------------- launch ----------------
extern "C" void kernel_launch(void* const* d_in, const int* in_sizes, int n_in,
                              void* d_out, int out_size, void* d_ws, size_t ws_size,
                              hipStream_t stream) {
  const float* x = (const float*)d_in[0];
  const float* Wq = (const float*)d_in[1];
  const float* bq = (const float*)d_in[2];
  const float* Wk = (const float*)d_in[3];
  const float* bk = (const float*)d_in[4];
  const float* Wv = (const float*)d_in[5];
  const float* bv = (const float*)d_in[6];
  const float* relh = (const float*)d_in[7];
  const float* relw = (const float*)d_in[8];

  char* ws = (char*)d_ws;
  const size_t MB = 1 << 20;
  f16* xT = (f16*)(ws);                         // 16MB
  f16* KQ = (f16*)(ws + 16 * MB);               // 32MB
  f16* V  = (f16*)(ws + 48 * MB);               // 16MB
  f16* RT = (f16*)(ws + 64 * MB);               // 512KB
  f16* Wh = (f16*)(ws + 64 * MB + 512 * 1024);  // 384KB

  k_prep<<<dim3(1216), dim3(256), 0, stream>>>(Wq, Wk, Wv, relh, relw, Wh, RT);
  k_xpose<<<dim3(2048), dim3(256), 0, stream>>>(x, xT);
  k_proj<<<dim3(512), dim3(256), 0, stream>>>(xT, Wh, bq, bk, bv, KQ, V);
  k_flash5<<<dim3(512), dim3(256), 0, stream>>>(KQ, V, RT, (float*)d_out);
}